// Round 5
// baseline (745.987 us; speedup 1.0000x reference)
//
#include <hip/hip_runtime.h>
#include <hip/hip_bf16.h>

// ---------------- problem constants ----------------
#define NN   20000
#define EE_  160000          // raw edges
#define ETOT (EE_ + NN)      // + self loops
#define GG   64
#define H1_  8
#define F1_  64
#define H2_  4
#define F2_  32
#define NEG_SLOPE 0.2f
#define BN_EPS 1e-5f

// ---------------- workspace layout (floats) ----------------
// zeroed region (single memset)
#define OFF_NUM1 0                         // N*8
#define OFF_Z1   (OFF_NUM1 + NN*8)        // N*8
#define OFF_Z2   (OFF_Z1   + NN*8)        // N*4
#define OFF_NUM2 (OFF_Z2   + NN*4)        // N*128
#define OFF_GSUM (OFF_NUM2 + NN*128)      // G*128
#define OFF_GCNT (OFF_GSUM + GG*128)      // G
#define ZTOTAL   (OFF_GCNT + GG)
// non-zeroed region (fully written each call before use)
#define OFF_C1   ((ZTOTAL + 63) & ~63)    // 16
#define OFF_FLAG (OFF_C1 + 16)            // 2 ints: [0]=idx wide, [1]=floats-are-bf16
#define OFF_H2   (OFF_C1 + 64)            // N*128
#define OFF_AS2  (OFF_H2 + NN*128)        // N*4
#define OFF_AD2  (OFF_AS2 + NN*4)         // N*4

__device__ __forceinline__ float lrelu(float v) { return v > 0.f ? v : NEG_SLOPE * v; }

// dual-width index read: wide=1 -> int64 buffer, wide=0 -> int32 buffer
__device__ __forceinline__ int rd_idx(const void* p, int i, int wide) {
    if (wide) return (int)((const long long*)p)[i];
    return ((const int*)p)[i];
}

// dual-dtype float read: bf=1 -> __hip_bfloat16 buffer, bf=0 -> float buffer
__device__ __forceinline__ float ldf(const void* p, int i, int bf) {
    if (bf) return __bfloat162float(((const __hip_bfloat16*)p)[i]);
    return ((const float*)p)[i];
}

// K0: dtype detection + c1 coefficients.
__global__ void k0_prep(const void* __restrict__ W1, const void* __restrict__ a1s,
                        const void* __restrict__ a1d, const void* __restrict__ ei,
                        const void* __restrict__ W2,
                        float* __restrict__ c1, int* __restrict__ flags) {
    __shared__ int sbf;
    int t = threadIdx.x;
    if (t == 0) {
        // Detect bf16 staging of float inputs using W2 (65536 elems per ref).
        // (Proven inert in rounds 1-4: flag stays 0 on this harness. Kept as a
        // guard; costs nothing.)
        const unsigned* w = (const unsigned*)W2;
        int sane = 0;
        for (int k = 0; k < 256; ++k) {
            unsigned lo = w[k * 64] & 0xffffu;
            int ex = (int)((lo >> 7) & 0xff);
            if (lo == 0u || (ex >= 100 && ex <= 140)) sane++;
        }
        sbf = (sane >= 128) ? 1 : 0;
        flags[1] = sbf;
    }
    if (t == 32) {
        // if edge_index is int64 (values < 2^31), every odd 32-bit word is 0.
        const int* w = (const int*)ei;
        int nz = 0;
        for (int k = 0; k < 256; ++k) nz |= w[2 * k + 1];
        flags[0] = (nz == 0) ? 1 : 0;
    }
    __syncthreads();
    const int bf = sbf;
    if (t < 16) {
        int h = t & 7;
        const void* a = (t & 8) ? a1d : a1s;
        float acc = 0.f;
        for (int f = 0; f < F1_; ++f)
            acc += ldf(W1, h * F1_ + f, bf) * ldf(a, h * F1_ + f, bf);
        c1[t] = acc;   // [0..7]=src coeff, [8..15]=dst coeff
    }
}

// K1: fused layer-1 attention pass. num1[d,h] += exp(e)*x[s]; z1[d,h] += exp(e)
__global__ __launch_bounds__(256) void k1_edge1(const void* __restrict__ x,
                                                const void* __restrict__ ei,
                                                const float* __restrict__ c1,
                                                const int* __restrict__ flags,
                                                float* __restrict__ num1,
                                                float* __restrict__ z1) {
    int e = blockIdx.x * 256 + threadIdx.x;
    if (e >= ETOT) return;
    const int wide = flags[0], bf = flags[1];
    int s, d;
    if (e < EE_) { s = rd_idx(ei, e, wide); d = rd_idx(ei, EE_ + e, wide); }
    else         { s = d = e - EE_; }
    float xs = ldf(x, s, bf), xd = ldf(x, d, bf);
#pragma unroll
    for (int h = 0; h < H1_; ++h) {
        float v = lrelu(xs * c1[h] + xd * c1[8 + h]);
        float w = __expf(v);
        atomicAdd(&num1[d * 8 + h], w * xs);
        atomicAdd(&z1[d * 8 + h], w);
    }
}

// K2: per 16 nodes: s=num1/z1 -> h1 row (512, LDS) -> h2 = h1@W2 (128) -> head dots
#define K2_NODES 16
__global__ __launch_bounds__(64) void k2_h2(const void* __restrict__ W1,
                                            const void* __restrict__ b1,
                                            const void* __restrict__ W2,
                                            const void* __restrict__ a2s,
                                            const void* __restrict__ a2d,
                                            const float* __restrict__ num1,
                                            const float* __restrict__ z1,
                                            const int* __restrict__ flags,
                                            float* __restrict__ h2,
                                            float* __restrict__ as2,
                                            float* __restrict__ ad2) {
    __shared__ float h1[K2_NODES][512];
    __shared__ float sv[K2_NODES][8];
    __shared__ float red[4][64];
    const int i0 = blockIdx.x * K2_NODES;
    const int t = threadIdx.x;
    const int bf = flags[1];

    for (int u = t; u < K2_NODES * 8; u += 64) {
        int n = u >> 3, h = u & 7;
        sv[n][h] = num1[(i0 + n) * 8 + h] / z1[(i0 + n) * 8 + h];
    }
    __syncthreads();
#pragma unroll
    for (int n = 0; n < K2_NODES; ++n)
        for (int c = t; c < 512; c += 64) {
            float v = ldf(W1, c, bf) * sv[n][c >> 6] + ldf(b1, c, bf);
            h1[n][c] = v > 0.f ? v : 0.f;
        }
    __syncthreads();

    const int o0 = t, o1 = t + 64;
    float acc0[K2_NODES] = {};
    float acc1[K2_NODES] = {};
    for (int c = 0; c < 512; c += 4) {
        float w00 = ldf(W2, (c + 0) * 128 + o0, bf);
        float w10 = ldf(W2, (c + 1) * 128 + o0, bf);
        float w20 = ldf(W2, (c + 2) * 128 + o0, bf);
        float w30 = ldf(W2, (c + 3) * 128 + o0, bf);
        float w01 = ldf(W2, (c + 0) * 128 + o1, bf);
        float w11 = ldf(W2, (c + 1) * 128 + o1, bf);
        float w21 = ldf(W2, (c + 2) * 128 + o1, bf);
        float w31 = ldf(W2, (c + 3) * 128 + o1, bf);
#pragma unroll
        for (int n = 0; n < K2_NODES; ++n) {
            const float4 hv = *reinterpret_cast<const float4*>(&h1[n][c]);
            acc0[n] = fmaf(hv.x, w00, acc0[n]);
            acc0[n] = fmaf(hv.y, w10, acc0[n]);
            acc0[n] = fmaf(hv.z, w20, acc0[n]);
            acc0[n] = fmaf(hv.w, w30, acc0[n]);
            acc1[n] = fmaf(hv.x, w01, acc1[n]);
            acc1[n] = fmaf(hv.y, w11, acc1[n]);
            acc1[n] = fmaf(hv.z, w21, acc1[n]);
            acc1[n] = fmaf(hv.w, w31, acc1[n]);
        }
    }

    const float a2s0 = ldf(a2s, o0, bf), a2d0 = ldf(a2d, o0, bf);
    const float a2s1 = ldf(a2s, o1, bf), a2d1 = ldf(a2d, o1, bf);
#pragma unroll
    for (int n = 0; n < K2_NODES; ++n) {
        const int i = i0 + n;
        h2[i * 128 + o0] = acc0[n];
        h2[i * 128 + o1] = acc1[n];
        red[0][t] = acc0[n] * a2s0;   // p0s
        red[1][t] = acc0[n] * a2d0;   // p0d
        red[2][t] = acc1[n] * a2s1;   // p1s
        red[3][t] = acc1[n] * a2d1;   // p1d
        __syncthreads();
        if (t < 8) {
            int q = t & 3, grp = t >> 2;
            float sacc = 0.f;
            for (int k = 0; k < 32; ++k) sacc += red[q][grp * 32 + k];
            int head = grp + ((q >= 2) ? 2 : 0);
            if (q & 1) ad2[i * 4 + head] = sacc;
            else       as2[i * 4 + head] = sacc;
        }
        __syncthreads();
    }
}

// K3: layer-2 edge aggregation. 1 wave per edge; 2 columns per lane.
__global__ __launch_bounds__(256) void k3_edge2(const void* __restrict__ ei,
                                                const int* __restrict__ flags,
                                                const float* __restrict__ h2,
                                                const float* __restrict__ as2,
                                                const float* __restrict__ ad2,
                                                float* __restrict__ num2,
                                                float* __restrict__ z2) {
    int e = blockIdx.x * 4 + (threadIdx.x >> 6);
    int lane = threadIdx.x & 63;
    if (e >= ETOT) return;
    const int wide = flags[0];
    int s, d;
    if (e < EE_) { s = rd_idx(ei, e, wide); d = rd_idx(ei, EE_ + e, wide); }
    else         { s = d = e - EE_; }
    int h0 = lane >> 5;        // 0/1
    int h1_ = 2 + h0;          // 2/3
    float w0 = __expf(lrelu(as2[s * 4 + h0] + ad2[d * 4 + h0]));
    float w1 = __expf(lrelu(as2[s * 4 + h1_] + ad2[d * 4 + h1_]));
    atomicAdd(&num2[d * 128 + lane],      w0 * h2[s * 128 + lane]);
    atomicAdd(&num2[d * 128 + lane + 64], w1 * h2[s * 128 + lane + 64]);
    if (lane < 4)
        atomicAdd(&z2[d * 4 + lane], __expf(lrelu(as2[s * 4 + lane] + ad2[d * 4 + lane])));
}

// K4: out2 = relu(num2/z2 + b2); mean-pool into gsum/gcnt (batch is sorted)
__global__ __launch_bounds__(128) void k4_pool(const float* __restrict__ num2,
                                               const float* __restrict__ z2,
                                               const void* __restrict__ b2,
                                               const void* __restrict__ batch,
                                               const int* __restrict__ flags,
                                               float* __restrict__ gsum,
                                               float* __restrict__ gcnt) {
    const int i0 = blockIdx.x * 64;
    if (i0 >= NN) return;
    const int wide = flags[0], bf = flags[1];
    const int o = threadIdx.x;
    const int iend = min(i0 + 64, NN);
    const float bo = ldf(b2, o, bf);
    float acc = 0.f, cnt = 0.f;
    int gcur = rd_idx(batch, i0, wide);
    for (int i = i0; i < iend; ++i) {
        int g = rd_idx(batch, i, wide);
        if (g != gcur) {
            atomicAdd(&gsum[gcur * 128 + o], acc);
            if (o == 0) atomicAdd(&gcnt[gcur], cnt);
            acc = 0.f; cnt = 0.f; gcur = g;
        }
        float v = num2[i * 128 + o] / z2[i * 4 + (o >> 5)] + bo;
        acc += (v > 0.f ? v : 0.f);
        cnt += 1.f;
    }
    atomicAdd(&gsum[gcur * 128 + o], acc);
    if (o == 0) atomicAdd(&gcnt[gcur], cnt);
}

// K5: fc -> batchnorm(batch stats) -> relu -> two small heads. One block of 64.
// OUTPUT IS FLOAT32 (reference output dtype is fp32; env contract: "else float*").
__global__ __launch_bounds__(64) void k5_head(const float* __restrict__ gsum,
                                              const float* __restrict__ gcnt,
                                              const void* __restrict__ fcW,
                                              const void* __restrict__ fcb,
                                              const void* __restrict__ gamma,
                                              const void* __restrict__ beta,
                                              const void* __restrict__ heatW,
                                              const void* __restrict__ heatb,
                                              const void* __restrict__ dehydW,
                                              const void* __restrict__ dehydb,
                                              const int* __restrict__ flags,
                                              float* __restrict__ out) {
    __shared__ float Y[GG][17];
    __shared__ float muA[16], ivA[16];
    const int g = threadIdx.x;
    const int bf = flags[1];

    float y[16];
#pragma unroll
    for (int j = 0; j < 16; ++j) y[j] = ldf(fcb, j, bf);
    const float cw = 1.f / fmaxf(gcnt[g], 1.f);
    for (int c = 0; c < 128; ++c) {
        float p = gsum[g * 128 + c] * cw;
#pragma unroll
        for (int j = 0; j < 16; ++j) y[j] = fmaf(p, ldf(fcW, c * 16 + j, bf), y[j]);
    }
#pragma unroll
    for (int j = 0; j < 16; ++j) Y[g][j] = y[j];
    __syncthreads();

    if (g < 16) {
        float mu = 0.f;
        for (int r = 0; r < GG; ++r) mu += Y[r][g];
        mu *= (1.f / GG);
        float var = 0.f;
        for (int r = 0; r < GG; ++r) { float dd = Y[r][g] - mu; var += dd * dd; }
        var *= (1.f / GG);
        muA[g] = mu;
        ivA[g] = rsqrtf(var + BN_EPS);
    }
    __syncthreads();

    float r[16];
#pragma unroll
    for (int j = 0; j < 16; ++j) {
        float v = (y[j] - muA[j]) * ivA[j] * ldf(gamma, j, bf) + ldf(beta, j, bf);
        r[j] = v > 0.f ? v : 0.f;
    }
#pragma unroll
    for (int k = 0; k < 3; ++k) {
        float acc = ldf(heatb, k, bf);
#pragma unroll
        for (int j = 0; j < 16; ++j) acc = fmaf(r[j], ldf(heatW, j * 3 + k, bf), acc);
        out[g * 3 + k] = acc;
    }
#pragma unroll
    for (int k = 0; k < 2; ++k) {
        float acc = ldf(dehydb, k, bf);
#pragma unroll
        for (int j = 0; j < 16; ++j) acc = fmaf(r[j], ldf(dehydW, j * 2 + k, bf), acc);
        out[GG * 3 + g * 2 + k] = acc;
    }
}

extern "C" void kernel_launch(void* const* d_in, const int* in_sizes, int n_in,
                              void* d_out, int out_size, void* d_ws, size_t ws_size,
                              hipStream_t stream) {
    const void* x      = d_in[0];
    const void* ei     = d_in[1];
    const void* batch  = d_in[2];
    const void* W1     = d_in[3];
    const void* a1s    = d_in[4];
    const void* a1d    = d_in[5];
    const void* b1     = d_in[6];
    const void* W2     = d_in[7];
    const void* a2s    = d_in[8];
    const void* a2d    = d_in[9];
    const void* b2     = d_in[10];
    const void* fcW    = d_in[11];
    const void* fcb    = d_in[12];
    const void* gamma  = d_in[13];
    const void* beta   = d_in[14];
    const void* heatW  = d_in[15];
    const void* heatb  = d_in[16];
    const void* dehydW = d_in[17];
    const void* dehydb = d_in[18];

    float* ws   = (float*)d_ws;
    float* num1 = ws + OFF_NUM1;
    float* z1   = ws + OFF_Z1;
    float* z2   = ws + OFF_Z2;
    float* num2 = ws + OFF_NUM2;
    float* gsum = ws + OFF_GSUM;
    float* gcnt = ws + OFF_GCNT;
    float* c1   = ws + OFF_C1;
    int*   flags= (int*)(ws + OFF_FLAG);
    float* h2   = ws + OFF_H2;
    float* as2  = ws + OFF_AS2;
    float* ad2  = ws + OFF_AD2;

    // zero all atomic accumulators in one shot
    hipMemsetAsync(ws, 0, (size_t)ZTOTAL * sizeof(float), stream);

    k0_prep<<<1, 64, 0, stream>>>(W1, a1s, a1d, ei, W2, c1, flags);
    k1_edge1<<<(ETOT + 255) / 256, 256, 0, stream>>>(x, ei, c1, flags, num1, z1);
    k2_h2<<<NN / K2_NODES, 64, 0, stream>>>(W1, b1, W2, a2s, a2d, num1, z1, flags, h2, as2, ad2);
    k3_edge2<<<(ETOT + 3) / 4, 256, 0, stream>>>(ei, flags, h2, as2, ad2, num2, z2);
    k4_pool<<<(NN + 63) / 64, 128, 0, stream>>>(num2, z2, b2, batch, flags, gsum, gcnt);
    k5_head<<<1, 64, 0, stream>>>(gsum, gcnt, fcW, fcb, gamma, beta,
                                  heatW, heatb, dehydW, dehydb, flags,
                                  (float*)d_out);
}

// Round 6
// 627.101 us; speedup vs baseline: 1.1896x; 1.1896x over previous
//
#include <hip/hip_runtime.h>
#include <hip/hip_bf16.h>

// ---------------- problem constants ----------------
#define NN   20000
#define EE_  160000          // raw edges
#define ETOT (EE_ + NN)      // + self loops
#define GG   64
#define H1_  8
#define F1_  64
#define H2_  4
#define F2_  32
#define NEG_SLOPE 0.2f
#define BN_EPS 1e-5f

// ---------------- workspace layout (floats) ----------------
// zeroed region (single memset)
#define OFF_NUM1 0                         // N*8
#define OFF_Z1   (OFF_NUM1 + NN*8)        // N*8
#define OFF_Z2   (OFF_Z1   + NN*8)        // N*4
#define OFF_NUM2 (OFF_Z2   + NN*4)        // N*128
#define OFF_GSUM (OFF_NUM2 + NN*128)      // G*128
#define OFF_GCNT (OFF_GSUM + GG*128)      // G
#define ZTOTAL   (OFF_GCNT + GG)
// non-zeroed region (fully written each call before use)
#define OFF_C1   ((ZTOTAL + 63) & ~63)    // 16
#define OFF_FLAG (OFF_C1 + 16)            // 2 ints: [0]=idx wide, [1]=floats-are-bf16
#define OFF_H2   (OFF_C1 + 64)            // N*128
#define OFF_AS2  (OFF_H2 + NN*128)        // N*4
#define OFF_AD2  (OFF_AS2 + NN*4)         // N*4

__device__ __forceinline__ float lrelu(float v) { return v > 0.f ? v : NEG_SLOPE * v; }

// dual-width index read: wide=1 -> int64 buffer, wide=0 -> int32 buffer
__device__ __forceinline__ int rd_idx(const void* p, int i, int wide) {
    if (wide) return (int)((const long long*)p)[i];
    return ((const int*)p)[i];
}

// dual-dtype float read: bf=1 -> __hip_bfloat16 buffer, bf=0 -> float buffer
__device__ __forceinline__ float ldf(const void* p, int i, int bf) {
    if (bf) return __bfloat162float(((const __hip_bfloat16*)p)[i]);
    return ((const float*)p)[i];
}

// K0: dtype detection + c1 coefficients.
__global__ void k0_prep(const void* __restrict__ W1, const void* __restrict__ a1s,
                        const void* __restrict__ a1d, const void* __restrict__ ei,
                        const void* __restrict__ W2,
                        float* __restrict__ c1, int* __restrict__ flags) {
    __shared__ int sbf;
    int t = threadIdx.x;
    if (t == 0) {
        const unsigned* w = (const unsigned*)W2;
        int sane = 0;
        for (int k = 0; k < 256; ++k) {
            unsigned lo = w[k * 64] & 0xffffu;
            int ex = (int)((lo >> 7) & 0xff);
            if (lo == 0u || (ex >= 100 && ex <= 140)) sane++;
        }
        sbf = (sane >= 128) ? 1 : 0;
        flags[1] = sbf;
    }
    if (t == 32) {
        const int* w = (const int*)ei;
        int nz = 0;
        for (int k = 0; k < 256; ++k) nz |= w[2 * k + 1];
        flags[0] = (nz == 0) ? 1 : 0;
    }
    __syncthreads();
    const int bf = sbf;
    if (t < 16) {
        int h = t & 7;
        const void* a = (t & 8) ? a1d : a1s;
        float acc = 0.f;
        for (int f = 0; f < F1_; ++f)
            acc += ldf(W1, h * F1_ + f, bf) * ldf(a, h * F1_ + f, bf);
        c1[t] = acc;   // [0..7]=src coeff, [8..15]=dst coeff
    }
}

// K1: fused layer-1 attention pass. num1[d,h] += exp(e)*x[s]; z1[d,h] += exp(e)
__global__ __launch_bounds__(256) void k1_edge1(const void* __restrict__ x,
                                                const void* __restrict__ ei,
                                                const float* __restrict__ c1,
                                                const int* __restrict__ flags,
                                                float* __restrict__ num1,
                                                float* __restrict__ z1) {
    int e = blockIdx.x * 256 + threadIdx.x;
    if (e >= ETOT) return;
    const int wide = flags[0], bf = flags[1];
    int s, d;
    if (e < EE_) { s = rd_idx(ei, e, wide); d = rd_idx(ei, EE_ + e, wide); }
    else         { s = d = e - EE_; }
    float xs = ldf(x, s, bf), xd = ldf(x, d, bf);
#pragma unroll
    for (int h = 0; h < H1_; ++h) {
        float v = lrelu(xs * c1[h] + xd * c1[8 + h]);
        float w = __expf(v);
        atomicAdd(&num1[d * 8 + h], w * xs);
        atomicAdd(&z1[d * 8 + h], w);
    }
}

// K2 (rewritten): 256 threads / 4 waves per block, 16 nodes per block.
// thread (o = t&127, grp = t>>7) computes h2[i0+grp*8 .. +7][o].
// Epilogue: in-wave __shfl_xor reductions for the 4 head dot products.
#define K2_NODES 16
__global__ __launch_bounds__(256) void k2_h2(const void* __restrict__ W1,
                                             const void* __restrict__ b1,
                                             const void* __restrict__ W2,
                                             const void* __restrict__ a2s,
                                             const void* __restrict__ a2d,
                                             const float* __restrict__ num1,
                                             const float* __restrict__ z1,
                                             const int* __restrict__ flags,
                                             float* __restrict__ h2,
                                             float* __restrict__ as2,
                                             float* __restrict__ ad2) {
    __shared__ float h1[K2_NODES][512];   // 32 KB
    __shared__ float sv[K2_NODES][8];
    const int i0 = blockIdx.x * K2_NODES;
    const int t = threadIdx.x;
    const int bf = flags[1];

    if (t < K2_NODES * 8) {
        int n = t >> 3, h = t & 7;
        sv[n][h] = num1[(i0 + n) * 8 + h] / z1[(i0 + n) * 8 + h];
    }
    __syncthreads();

    // h1 build: thread owns columns t and t+256 for all 16 nodes.
    {
        const float w1a = ldf(W1, t, bf),       w1b = ldf(W1, t + 256, bf);
        const float b1a = ldf(b1, t, bf),       b1b = ldf(b1, t + 256, bf);
        const int   ha  = t >> 6,               hb  = (t + 256) >> 6;
#pragma unroll
        for (int n = 0; n < K2_NODES; ++n) {
            float va = fmaf(w1a, sv[n][ha], b1a);
            float vb = fmaf(w1b, sv[n][hb], b1b);
            h1[n][t]       = va > 0.f ? va : 0.f;
            h1[n][t + 256] = vb > 0.f ? vb : 0.f;
        }
    }
    __syncthreads();

    const int o  = t & 127;
    const int nb = (t >> 7) * 8;     // node base for this half-block
    float acc[8] = {};
    for (int c = 0; c < 512; c += 4) {
        const float w0 = ldf(W2, (c + 0) * 128 + o, bf);
        const float w1 = ldf(W2, (c + 1) * 128 + o, bf);
        const float w2 = ldf(W2, (c + 2) * 128 + o, bf);
        const float w3 = ldf(W2, (c + 3) * 128 + o, bf);
#pragma unroll
        for (int n = 0; n < 8; ++n) {
            const float4 hv = *reinterpret_cast<const float4*>(&h1[nb + n][c]);
            acc[n] = fmaf(hv.x, w0, acc[n]);
            acc[n] = fmaf(hv.y, w1, acc[n]);
            acc[n] = fmaf(hv.z, w2, acc[n]);
            acc[n] = fmaf(hv.w, w3, acc[n]);
        }
    }

    // epilogue: h2 store + head dots via 32-lane shuffle reduction.
    const float as_ = ldf(a2s, o, bf);
    const float ad_ = ldf(a2d, o, bf);
    const int head = o >> 5;          // this lane's head (32 cols per head)
    const int lane = t & 63;
#pragma unroll
    for (int n = 0; n < 8; ++n) {
        const int i = i0 + nb + n;
        h2[i * 128 + o] = acc[n];
        float ps = acc[n] * as_;
        float pd = acc[n] * ad_;
#pragma unroll
        for (int sh = 16; sh; sh >>= 1) {   // masks 16,8,4,2,1 stay within 32-lane group
            ps += __shfl_xor(ps, sh);
            pd += __shfl_xor(pd, sh);
        }
        if ((lane & 31) == 0) {
            as2[i * 4 + head] = ps;
            ad2[i * 4 + head] = pd;
        }
    }
}

// K3: layer-2 edge aggregation. 1 wave per edge; 2 columns per lane.
__global__ __launch_bounds__(256) void k3_edge2(const void* __restrict__ ei,
                                                const int* __restrict__ flags,
                                                const float* __restrict__ h2,
                                                const float* __restrict__ as2,
                                                const float* __restrict__ ad2,
                                                float* __restrict__ num2,
                                                float* __restrict__ z2) {
    int e = blockIdx.x * 4 + (threadIdx.x >> 6);
    int lane = threadIdx.x & 63;
    if (e >= ETOT) return;
    const int wide = flags[0];
    int s, d;
    if (e < EE_) { s = rd_idx(ei, e, wide); d = rd_idx(ei, EE_ + e, wide); }
    else         { s = d = e - EE_; }
    int h0 = lane >> 5;        // 0/1
    int h1_ = 2 + h0;          // 2/3
    float w0 = __expf(lrelu(as2[s * 4 + h0] + ad2[d * 4 + h0]));
    float w1 = __expf(lrelu(as2[s * 4 + h1_] + ad2[d * 4 + h1_]));
    atomicAdd(&num2[d * 128 + lane],      w0 * h2[s * 128 + lane]);
    atomicAdd(&num2[d * 128 + lane + 64], w1 * h2[s * 128 + lane + 64]);
    if (lane < 4)
        atomicAdd(&z2[d * 4 + lane], __expf(lrelu(as2[s * 4 + lane] + ad2[d * 4 + lane])));
}

// K4: out2 = relu(num2/z2 + b2); mean-pool into gsum/gcnt (batch is sorted)
__global__ __launch_bounds__(128) void k4_pool(const float* __restrict__ num2,
                                               const float* __restrict__ z2,
                                               const void* __restrict__ b2,
                                               const void* __restrict__ batch,
                                               const int* __restrict__ flags,
                                               float* __restrict__ gsum,
                                               float* __restrict__ gcnt) {
    const int i0 = blockIdx.x * 64;
    if (i0 >= NN) return;
    const int wide = flags[0], bf = flags[1];
    const int o = threadIdx.x;
    const int iend = min(i0 + 64, NN);
    const float bo = ldf(b2, o, bf);
    float acc = 0.f, cnt = 0.f;
    int gcur = rd_idx(batch, i0, wide);
    for (int i = i0; i < iend; ++i) {
        int g = rd_idx(batch, i, wide);
        if (g != gcur) {
            atomicAdd(&gsum[gcur * 128 + o], acc);
            if (o == 0) atomicAdd(&gcnt[gcur], cnt);
            acc = 0.f; cnt = 0.f; gcur = g;
        }
        float v = num2[i * 128 + o] / z2[i * 4 + (o >> 5)] + bo;
        acc += (v > 0.f ? v : 0.f);
        cnt += 1.f;
    }
    atomicAdd(&gsum[gcur * 128 + o], acc);
    if (o == 0) atomicAdd(&gcnt[gcur], cnt);
}

// K5: fc -> batchnorm(batch stats) -> relu -> two small heads. One block of 64.
// OUTPUT IS FLOAT32 (reference output dtype is fp32).
__global__ __launch_bounds__(64) void k5_head(const float* __restrict__ gsum,
                                              const float* __restrict__ gcnt,
                                              const void* __restrict__ fcW,
                                              const void* __restrict__ fcb,
                                              const void* __restrict__ gamma,
                                              const void* __restrict__ beta,
                                              const void* __restrict__ heatW,
                                              const void* __restrict__ heatb,
                                              const void* __restrict__ dehydW,
                                              const void* __restrict__ dehydb,
                                              const int* __restrict__ flags,
                                              float* __restrict__ out) {
    __shared__ float Y[GG][17];
    __shared__ float muA[16], ivA[16];
    const int g = threadIdx.x;
    const int bf = flags[1];

    float y[16];
#pragma unroll
    for (int j = 0; j < 16; ++j) y[j] = ldf(fcb, j, bf);
    const float cw = 1.f / fmaxf(gcnt[g], 1.f);
    for (int c = 0; c < 128; ++c) {
        float p = gsum[g * 128 + c] * cw;
#pragma unroll
        for (int j = 0; j < 16; ++j) y[j] = fmaf(p, ldf(fcW, c * 16 + j, bf), y[j]);
    }
#pragma unroll
    for (int j = 0; j < 16; ++j) Y[g][j] = y[j];
    __syncthreads();

    if (g < 16) {
        float mu = 0.f;
        for (int r = 0; r < GG; ++r) mu += Y[r][g];
        mu *= (1.f / GG);
        float var = 0.f;
        for (int r = 0; r < GG; ++r) { float dd = Y[r][g] - mu; var += dd * dd; }
        var *= (1.f / GG);
        muA[g] = mu;
        ivA[g] = rsqrtf(var + BN_EPS);
    }
    __syncthreads();

    float r[16];
#pragma unroll
    for (int j = 0; j < 16; ++j) {
        float v = (y[j] - muA[j]) * ivA[j] * ldf(gamma, j, bf) + ldf(beta, j, bf);
        r[j] = v > 0.f ? v : 0.f;
    }
#pragma unroll
    for (int k = 0; k < 3; ++k) {
        float acc = ldf(heatb, k, bf);
#pragma unroll
        for (int j = 0; j < 16; ++j) acc = fmaf(r[j], ldf(heatW, j * 3 + k, bf), acc);
        out[g * 3 + k] = acc;
    }
#pragma unroll
    for (int k = 0; k < 2; ++k) {
        float acc = ldf(dehydb, k, bf);
#pragma unroll
        for (int j = 0; j < 16; ++j) acc = fmaf(r[j], ldf(dehydW, j * 2 + k, bf), acc);
        out[GG * 3 + g * 2 + k] = acc;
    }
}

extern "C" void kernel_launch(void* const* d_in, const int* in_sizes, int n_in,
                              void* d_out, int out_size, void* d_ws, size_t ws_size,
                              hipStream_t stream) {
    const void* x      = d_in[0];
    const void* ei     = d_in[1];
    const void* batch  = d_in[2];
    const void* W1     = d_in[3];
    const void* a1s    = d_in[4];
    const void* a1d    = d_in[5];
    const void* b1     = d_in[6];
    const void* W2     = d_in[7];
    const void* a2s    = d_in[8];
    const void* a2d    = d_in[9];
    const void* b2     = d_in[10];
    const void* fcW    = d_in[11];
    const void* fcb    = d_in[12];
    const void* gamma  = d_in[13];
    const void* beta   = d_in[14];
    const void* heatW  = d_in[15];
    const void* heatb  = d_in[16];
    const void* dehydW = d_in[17];
    const void* dehydb = d_in[18];

    float* ws   = (float*)d_ws;
    float* num1 = ws + OFF_NUM1;
    float* z1   = ws + OFF_Z1;
    float* z2   = ws + OFF_Z2;
    float* num2 = ws + OFF_NUM2;
    float* gsum = ws + OFF_GSUM;
    float* gcnt = ws + OFF_GCNT;
    float* c1   = ws + OFF_C1;
    int*   flags= (int*)(ws + OFF_FLAG);
    float* h2   = ws + OFF_H2;
    float* as2  = ws + OFF_AS2;
    float* ad2  = ws + OFF_AD2;

    // zero all atomic accumulators in one shot
    hipMemsetAsync(ws, 0, (size_t)ZTOTAL * sizeof(float), stream);

    k0_prep<<<1, 64, 0, stream>>>(W1, a1s, a1d, ei, W2, c1, flags);
    k1_edge1<<<(ETOT + 255) / 256, 256, 0, stream>>>(x, ei, c1, flags, num1, z1);
    k2_h2<<<NN / K2_NODES, 256, 0, stream>>>(W1, b1, W2, a2s, a2d, num1, z1, flags, h2, as2, ad2);
    k3_edge2<<<(ETOT + 3) / 4, 256, 0, stream>>>(ei, flags, h2, as2, ad2, num2, z2);
    k4_pool<<<(NN + 63) / 64, 128, 0, stream>>>(num2, z2, b2, batch, flags, gsum, gcnt);
    k5_head<<<1, 64, 0, stream>>>(gsum, gcnt, fcW, fcb, gamma, beta,
                                  heatW, heatb, dehydW, dehydb, flags,
                                  (float*)d_out);
}

// Round 7
// 416.744 us; speedup vs baseline: 1.7900x; 1.5048x over previous
//
#include <hip/hip_runtime.h>
#include <hip/hip_bf16.h>

// ---------------- problem constants ----------------
#define NN   20000
#define EE_  160000          // raw edges
#define ETOT (EE_ + NN)      // + self loops
#define GG   64
#define H1_  8
#define F1_  64
#define H2_  4
#define F2_  32
#define NEG_SLOPE 0.2f
#define BN_EPS 1e-5f

// ---------------- workspace layout (floats) ----------------
// zeroed region (single memset)
#define OFF_NUM1 0                         // N*8
#define OFF_Z1   (OFF_NUM1 + NN*8)        // N*8
#define OFF_Z2   (OFF_Z1   + NN*8)        // N*4
#define OFF_NUM2 (OFF_Z2   + NN*4)        // N*128
#define OFF_GSUM (OFF_NUM2 + NN*128)      // G*128
#define OFF_GCNT (OFF_GSUM + GG*128)      // G
#define ZTOTAL   (OFF_GCNT + GG)
// non-zeroed region (fully written each call before use)
#define OFF_C1   ((ZTOTAL + 63) & ~63)    // 16
#define OFF_H2   (OFF_C1 + 64)            // N*128
#define OFF_AS2  (OFF_H2 + NN*128)        // N*4
#define OFF_AD2  (OFF_AS2 + NN*4)         // N*4

__device__ __forceinline__ float lrelu(float v) { return v > 0.f ? v : NEG_SLOPE * v; }

// K0: c1 coefficients. 16 pairs (h, src/dst) x 8 lanes each; shfl_xor reduce.
__global__ __launch_bounds__(128) void k0_prep(const float* __restrict__ W1,
                                               const float* __restrict__ a1s,
                                               const float* __restrict__ a1d,
                                               float* __restrict__ c1) {
    const int t = threadIdx.x;          // 0..127
    const int pair = t >> 3;            // 0..15: [0..7]=src, [8..15]=dst
    const int f8 = t & 7;
    const int h = pair & 7;
    const float* a = (pair & 8) ? a1d : a1s;
    float acc = 0.f;
#pragma unroll
    for (int k = 0; k < 8; ++k) {
        int idx = h * F1_ + f8 + 8 * k;
        acc += W1[idx] * a[idx];
    }
#pragma unroll
    for (int sh = 4; sh; sh >>= 1) acc += __shfl_xor(acc, sh);  // reduce 8 lanes
    if (f8 == 0) c1[pair] = acc;
}

// K1: fused layer-1 attention pass. num1[d,h] += exp(e)*x[s]; z1[d,h] += exp(e)
__global__ __launch_bounds__(256) void k1_edge1(const float* __restrict__ x,
                                                const int* __restrict__ ei,
                                                const float* __restrict__ c1,
                                                float* __restrict__ num1,
                                                float* __restrict__ z1) {
    int e = blockIdx.x * 256 + threadIdx.x;
    if (e >= ETOT) return;
    int s, d;
    if (e < EE_) { s = ei[e]; d = ei[EE_ + e]; }
    else         { s = d = e - EE_; }
    float xs = x[s], xd = x[d];
#pragma unroll
    for (int h = 0; h < H1_; ++h) {
        float v = lrelu(xs * c1[h] + xd * c1[8 + h]);
        float w = __expf(v);
        atomicAdd(&num1[d * 8 + h], w * xs);
        atomicAdd(&z1[d * 8 + h], w);
    }
}

// K2: 256 threads / 4 waves per block, 16 nodes per block.
#define K2_NODES 16
__global__ __launch_bounds__(256) void k2_h2(const float* __restrict__ W1,
                                             const float* __restrict__ b1,
                                             const float* __restrict__ W2,
                                             const float* __restrict__ a2s,
                                             const float* __restrict__ a2d,
                                             const float* __restrict__ num1,
                                             const float* __restrict__ z1,
                                             float* __restrict__ h2,
                                             float* __restrict__ as2,
                                             float* __restrict__ ad2) {
    __shared__ float h1[K2_NODES][512];   // 32 KB
    __shared__ float sv[K2_NODES][8];
    const int i0 = blockIdx.x * K2_NODES;
    const int t = threadIdx.x;

    if (t < K2_NODES * 8) {
        int n = t >> 3, h = t & 7;
        sv[n][h] = num1[(i0 + n) * 8 + h] / z1[(i0 + n) * 8 + h];
    }
    __syncthreads();

    // h1 build: thread owns columns t and t+256 for all 16 nodes.
    {
        const float w1a = W1[t],     w1b = W1[t + 256];
        const float b1a = b1[t],     b1b = b1[t + 256];
        const int   ha  = t >> 6,    hb  = (t + 256) >> 6;
#pragma unroll
        for (int n = 0; n < K2_NODES; ++n) {
            float va = fmaf(w1a, sv[n][ha], b1a);
            float vb = fmaf(w1b, sv[n][hb], b1b);
            h1[n][t]       = va > 0.f ? va : 0.f;
            h1[n][t + 256] = vb > 0.f ? vb : 0.f;
        }
    }
    __syncthreads();

    const int o  = t & 127;
    const int nb = (t >> 7) * 8;     // node base for this half-block
    float acc[8] = {};
    for (int c = 0; c < 512; c += 4) {
        const float w0 = W2[(c + 0) * 128 + o];
        const float w1 = W2[(c + 1) * 128 + o];
        const float w2 = W2[(c + 2) * 128 + o];
        const float w3 = W2[(c + 3) * 128 + o];
#pragma unroll
        for (int n = 0; n < 8; ++n) {
            const float4 hv = *reinterpret_cast<const float4*>(&h1[nb + n][c]);
            acc[n] = fmaf(hv.x, w0, acc[n]);
            acc[n] = fmaf(hv.y, w1, acc[n]);
            acc[n] = fmaf(hv.z, w2, acc[n]);
            acc[n] = fmaf(hv.w, w3, acc[n]);
        }
    }

    // epilogue: h2 store + head dots via 32-lane shuffle reduction.
    const float as_ = a2s[o];
    const float ad_ = a2d[o];
    const int head = o >> 5;
    const int lane = t & 63;
#pragma unroll
    for (int n = 0; n < 8; ++n) {
        const int i = i0 + nb + n;
        h2[i * 128 + o] = acc[n];
        float ps = acc[n] * as_;
        float pd = acc[n] * ad_;
#pragma unroll
        for (int sh = 16; sh; sh >>= 1) {
            ps += __shfl_xor(ps, sh);
            pd += __shfl_xor(pd, sh);
        }
        if ((lane & 31) == 0) {
            as2[i * 4 + head] = ps;
            ad2[i * 4 + head] = pd;
        }
    }
}

// K3: layer-2 edge aggregation. 1 wave per edge; 2 columns per lane.
__global__ __launch_bounds__(256) void k3_edge2(const int* __restrict__ ei,
                                                const float* __restrict__ h2,
                                                const float* __restrict__ as2,
                                                const float* __restrict__ ad2,
                                                float* __restrict__ num2,
                                                float* __restrict__ z2) {
    int e = blockIdx.x * 4 + (threadIdx.x >> 6);
    int lane = threadIdx.x & 63;
    if (e >= ETOT) return;
    int s, d;
    if (e < EE_) { s = ei[e]; d = ei[EE_ + e]; }
    else         { s = d = e - EE_; }
    int h0 = lane >> 5;
    int h1_ = 2 + h0;
    float w0 = __expf(lrelu(as2[s * 4 + h0] + ad2[d * 4 + h0]));
    float w1 = __expf(lrelu(as2[s * 4 + h1_] + ad2[d * 4 + h1_]));
    atomicAdd(&num2[d * 128 + lane],      w0 * h2[s * 128 + lane]);
    atomicAdd(&num2[d * 128 + lane + 64], w1 * h2[s * 128 + lane + 64]);
    if (lane < 4)
        atomicAdd(&z2[d * 4 + lane], __expf(lrelu(as2[s * 4 + lane] + ad2[d * 4 + lane])));
}

// K4: out2 = relu(num2/z2 + b2); mean-pool into gsum/gcnt (batch is sorted)
__global__ __launch_bounds__(128) void k4_pool(const float* __restrict__ num2,
                                               const float* __restrict__ z2,
                                               const float* __restrict__ b2,
                                               const int* __restrict__ batch,
                                               float* __restrict__ gsum,
                                               float* __restrict__ gcnt) {
    const int i0 = blockIdx.x * 64;
    if (i0 >= NN) return;
    const int o = threadIdx.x;
    const int iend = min(i0 + 64, NN);
    const float bo = b2[o];
    float acc = 0.f, cnt = 0.f;
    int gcur = batch[i0];
    for (int i = i0; i < iend; ++i) {
        int g = batch[i];
        if (g != gcur) {
            atomicAdd(&gsum[gcur * 128 + o], acc);
            if (o == 0) atomicAdd(&gcnt[gcur], cnt);
            acc = 0.f; cnt = 0.f; gcur = g;
        }
        float v = num2[i * 128 + o] / z2[i * 4 + (o >> 5)] + bo;
        acc += (v > 0.f ? v : 0.f);
        cnt += 1.f;
    }
    atomicAdd(&gsum[gcur * 128 + o], acc);
    if (o == 0) atomicAdd(&gcnt[gcur], cnt);
}

// K5 (rewritten, parallel): one block, 256 threads.
// Phase A: stage pooled[64][129] (padded) + fcW in LDS, coalesced.
// Phase B: 1024 (g,j) dots over 256 threads (4 each).
// Phase C: BN stats via parallel partials; Phase D: heads (64 threads).
__global__ __launch_bounds__(256) void k5_head(const float* __restrict__ gsum,
                                               const float* __restrict__ gcnt,
                                               const float* __restrict__ fcW,
                                               const float* __restrict__ fcb,
                                               const float* __restrict__ gamma,
                                               const float* __restrict__ beta,
                                               const float* __restrict__ heatW,
                                               const float* __restrict__ heatb,
                                               const float* __restrict__ dehydW,
                                               const float* __restrict__ dehydb,
                                               float* __restrict__ out) {
    __shared__ float pl[GG][129];     // pooled, padded (129 breaks bank aliasing)
    __shared__ float fw[128 * 16];    // fcW staged
    __shared__ float cwS[GG];
    __shared__ float Y[GG][17];
    __shared__ float P[4][16], Q[4][16];
    __shared__ float muA[16], ivA[16];
    const int t = threadIdx.x;

    if (t < GG) cwS[t] = 1.f / fmaxf(gcnt[t], 1.f);
    for (int idx = t; idx < 128 * 16; idx += 256) fw[idx] = fcW[idx];
    __syncthreads();
    for (int idx = t; idx < GG * 128; idx += 256)
        pl[idx >> 7][idx & 127] = gsum[idx] * cwS[idx >> 7];
    __syncthreads();

    // fc: thread t handles g = t>>2, j in {jq, jq+4, jq+8, jq+12}
    {
        const int g = t >> 2, jq = t & 3;
        float y0 = fcb[jq], y1 = fcb[jq + 4], y2 = fcb[jq + 8], y3 = fcb[jq + 12];
        for (int c = 0; c < 128; ++c) {
            const float p = pl[g][c];
            const float* fr = &fw[c * 16];
            y0 = fmaf(p, fr[jq],      y0);
            y1 = fmaf(p, fr[jq + 4],  y1);
            y2 = fmaf(p, fr[jq + 8],  y2);
            y3 = fmaf(p, fr[jq + 12], y3);
        }
        Y[g][jq] = y0; Y[g][jq + 4] = y1; Y[g][jq + 8] = y2; Y[g][jq + 12] = y3;
    }
    __syncthreads();

    // BN stats: partials over 4 g-groups of 16
    if (t < 64) {
        const int j = t & 15, grp = t >> 4;
        float s = 0.f, q = 0.f;
        for (int k = 0; k < 16; ++k) {
            float v = Y[grp * 16 + k][j];
            s += v; q += v * v;
        }
        P[grp][j] = s; Q[grp][j] = q;
    }
    __syncthreads();
    if (t < 16) {
        float s = P[0][t] + P[1][t] + P[2][t] + P[3][t];
        float q = Q[0][t] + Q[1][t] + Q[2][t] + Q[3][t];
        float mu = s * (1.f / GG);
        float var = q * (1.f / GG) - mu * mu;
        muA[t] = mu;
        ivA[t] = rsqrtf(var + BN_EPS);
    }
    __syncthreads();

    if (t < GG) {
        const int g = t;
        float r[16];
#pragma unroll
        for (int j = 0; j < 16; ++j) {
            float v = (Y[g][j] - muA[j]) * ivA[j] * gamma[j] + beta[j];
            r[j] = v > 0.f ? v : 0.f;
        }
#pragma unroll
        for (int k = 0; k < 3; ++k) {
            float acc = heatb[k];
#pragma unroll
            for (int j = 0; j < 16; ++j) acc = fmaf(r[j], heatW[j * 3 + k], acc);
            out[g * 3 + k] = acc;
        }
#pragma unroll
        for (int k = 0; k < 2; ++k) {
            float acc = dehydb[k];
#pragma unroll
            for (int j = 0; j < 16; ++j) acc = fmaf(r[j], dehydW[j * 2 + k], acc);
            out[GG * 3 + g * 2 + k] = acc;
        }
    }
}

extern "C" void kernel_launch(void* const* d_in, const int* in_sizes, int n_in,
                              void* d_out, int out_size, void* d_ws, size_t ws_size,
                              hipStream_t stream) {
    const float* x      = (const float*)d_in[0];
    const int*   ei     = (const int*)  d_in[1];
    const int*   batch  = (const int*)  d_in[2];
    const float* W1     = (const float*)d_in[3];
    const float* a1s    = (const float*)d_in[4];
    const float* a1d    = (const float*)d_in[5];
    const float* b1     = (const float*)d_in[6];
    const float* W2     = (const float*)d_in[7];
    const float* a2s    = (const float*)d_in[8];
    const float* a2d    = (const float*)d_in[9];
    const float* b2     = (const float*)d_in[10];
    const float* fcW    = (const float*)d_in[11];
    const float* fcb    = (const float*)d_in[12];
    const float* gamma  = (const float*)d_in[13];
    const float* beta   = (const float*)d_in[14];
    const float* heatW  = (const float*)d_in[15];
    const float* heatb  = (const float*)d_in[16];
    const float* dehydW = (const float*)d_in[17];
    const float* dehydb = (const float*)d_in[18];

    float* ws   = (float*)d_ws;
    float* num1 = ws + OFF_NUM1;
    float* z1   = ws + OFF_Z1;
    float* z2   = ws + OFF_Z2;
    float* num2 = ws + OFF_NUM2;
    float* gsum = ws + OFF_GSUM;
    float* gcnt = ws + OFF_GCNT;
    float* c1   = ws + OFF_C1;
    float* h2   = ws + OFF_H2;
    float* as2  = ws + OFF_AS2;
    float* ad2  = ws + OFF_AD2;

    // zero all atomic accumulators in one shot
    hipMemsetAsync(ws, 0, (size_t)ZTOTAL * sizeof(float), stream);

    k0_prep<<<1, 128, 0, stream>>>(W1, a1s, a1d, c1);
    k1_edge1<<<(ETOT + 255) / 256, 256, 0, stream>>>(x, ei, c1, num1, z1);
    k2_h2<<<NN / K2_NODES, 256, 0, stream>>>(W1, b1, W2, a2s, a2d, num1, z1, h2, as2, ad2);
    k3_edge2<<<(ETOT + 3) / 4, 256, 0, stream>>>(ei, h2, as2, ad2, num2, z2);
    k4_pool<<<(NN + 63) / 64, 128, 0, stream>>>(num2, z2, b2, batch, gsum, gcnt);
    k5_head<<<1, 256, 0, stream>>>(gsum, gcnt, fcW, fcb, gamma, beta,
                                   heatW, heatb, dehydW, dehydb,
                                   (float*)d_out);
}

// Round 8
// 264.919 us; speedup vs baseline: 2.8159x; 1.5731x over previous
//
#include <hip/hip_runtime.h>
#include <hip/hip_bf16.h>

// ---------------- problem constants ----------------
#define NN   20000
#define EE_  160000          // raw edges
#define ETOT (EE_ + NN)      // + self loops
#define GG   64
#define H1_  8
#define F1_  64
#define NEG_SLOPE 0.2f
#define BN_EPS 1e-5f

// ---------------- workspace layout (float/int units) ----------------
// zeroed region (single memset): gsum, gcnt, deg
#define OFF_GSUM 0                        // G*128 floats
#define OFF_GCNT (OFF_GSUM + GG*128)      // G floats
#define OFF_DEG  (OFF_GCNT + GG)          // NN ints
#define ZTOTAL   (OFF_DEG + NN)
// non-zeroed region (fully written each call before use)
#define OFF_C1   ((ZTOTAL + 63) & ~63)    // 16 floats
#define OFF_SV   (OFF_C1 + 64)            // NN*8 floats
#define OFF_H2   (OFF_SV + NN*8)          // NN*128 floats
#define OFF_AS2  (OFF_H2 + NN*128)        // NN*4 floats
#define OFF_AD2  (OFF_AS2 + NN*4)         // NN*4 floats
#define OFF_OUT2 (OFF_AD2 + NN*4)         // NN*128 floats
#define OFF_OFFS (OFF_OUT2 + NN*128)      // NN+1 ints
#define OFF_CUR  (OFF_OFFS + NN + 1)      // NN ints
#define OFF_SSRC (OFF_CUR + NN)           // ETOT ints

__device__ __forceinline__ float lrelu(float v) { return v > 0.f ? v : NEG_SLOPE * v; }

// K0: c1 coefficients. 16 pairs (h, src/dst) x 8 lanes each; shfl_xor reduce.
__global__ __launch_bounds__(128) void k0_prep(const float* __restrict__ W1,
                                               const float* __restrict__ a1s,
                                               const float* __restrict__ a1d,
                                               float* __restrict__ c1) {
    const int t = threadIdx.x;
    const int pair = t >> 3;            // 0..15: [0..7]=src, [8..15]=dst
    const int f8 = t & 7;
    const int h = pair & 7;
    const float* a = (pair & 8) ? a1d : a1s;
    float acc = 0.f;
#pragma unroll
    for (int k = 0; k < 8; ++k) {
        int idx = h * F1_ + f8 + 8 * k;
        acc += W1[idx] * a[idx];
    }
#pragma unroll
    for (int sh = 4; sh; sh >>= 1) acc += __shfl_xor(acc, sh);
    if (f8 == 0) c1[pair] = acc;
}

// S0: in-degree histogram over all edges (incl. self loops)
__global__ __launch_bounds__(256) void s0_hist(const int* __restrict__ ei,
                                               int* __restrict__ deg) {
    int e = blockIdx.x * 256 + threadIdx.x;
    if (e >= ETOT) return;
    int d = (e < EE_) ? ei[EE_ + e] : (e - EE_);
    atomicAdd(&deg[d], 1);
}

// S1: exclusive scan of deg[NN] -> off[NN+1]; copy to cur.
__global__ __launch_bounds__(1024) void s1_scan(const int* __restrict__ deg,
                                                int* __restrict__ off,
                                                int* __restrict__ cur) {
    __shared__ int part[1024];
    const int t = threadIdx.x;
    const int base = t * 20;
    int loc[20];
    int sum = 0;
#pragma unroll
    for (int k = 0; k < 20; ++k) {
        int i = base + k;
        int v = (i < NN) ? deg[i] : 0;
        loc[k] = sum;
        sum += v;
    }
    part[t] = sum;
    __syncthreads();
    for (int sh = 1; sh < 1024; sh <<= 1) {
        int v = (t >= sh) ? part[t - sh] : 0;
        __syncthreads();
        part[t] += v;
        __syncthreads();
    }
    const int pbase = (t > 0) ? part[t - 1] : 0;
#pragma unroll
    for (int k = 0; k < 20; ++k) {
        int i = base + k;
        if (i < NN) {
            int o = pbase + loc[k];
            off[i] = o;
            cur[i] = o;
        }
    }
    if (t == 1023) off[NN] = part[1023];
}

// S2: scatter src ids into dst-sorted order
__global__ __launch_bounds__(256) void s2_scatter(const int* __restrict__ ei,
                                                  int* __restrict__ cur,
                                                  int* __restrict__ ssrc) {
    int e = blockIdx.x * 256 + threadIdx.x;
    if (e >= ETOT) return;
    int s, d;
    if (e < EE_) { s = ei[e]; d = ei[EE_ + e]; }
    else         { s = d = e - EE_; }
    int pos = atomicAdd(&cur[d], 1);
    ssrc[pos] = s;
}

// K1n: layer-1 attention, gather form. One thread per node; writes sv = num/z.
__global__ __launch_bounds__(256) void k1_gather(const float* __restrict__ x,
                                                 const int* __restrict__ off,
                                                 const int* __restrict__ ssrc,
                                                 const float* __restrict__ c1,
                                                 float* __restrict__ sv) {
    const int i = blockIdx.x * 256 + threadIdx.x;
    if (i >= NN) return;
    const float xd = x[i];
    float num[H1_] = {}, z[H1_] = {};
    const int a = off[i], b = off[i + 1];
    for (int j = a; j < b; ++j) {
        const int s = ssrc[j];
        const float xs = x[s];
#pragma unroll
        for (int h = 0; h < H1_; ++h) {
            float w = __expf(lrelu(xs * c1[h] + xd * c1[8 + h]));
            num[h] += w * xs;
            z[h] += w;
        }
    }
#pragma unroll
    for (int h = 0; h < H1_; ++h) sv[i * 8 + h] = num[h] / z[h];
}

// K2: 256 threads / 4 waves per block, 16 nodes per block. h2 = relu(h1)@W2.
#define K2_NODES 16
__global__ __launch_bounds__(256) void k2_h2(const float* __restrict__ W1,
                                             const float* __restrict__ b1,
                                             const float* __restrict__ W2,
                                             const float* __restrict__ a2s,
                                             const float* __restrict__ a2d,
                                             const float* __restrict__ svg,
                                             float* __restrict__ h2,
                                             float* __restrict__ as2,
                                             float* __restrict__ ad2) {
    __shared__ float h1[K2_NODES][512];   // 32 KB
    __shared__ float sv[K2_NODES][8];
    const int i0 = blockIdx.x * K2_NODES;
    const int t = threadIdx.x;

    if (t < K2_NODES * 8) {
        int n = t >> 3, h = t & 7;
        sv[n][h] = svg[(i0 + n) * 8 + h];
    }
    __syncthreads();

    {
        const float w1a = W1[t],     w1b = W1[t + 256];
        const float b1a = b1[t],     b1b = b1[t + 256];
        const int   ha  = t >> 6,    hb  = (t + 256) >> 6;
#pragma unroll
        for (int n = 0; n < K2_NODES; ++n) {
            float va = fmaf(w1a, sv[n][ha], b1a);
            float vb = fmaf(w1b, sv[n][hb], b1b);
            h1[n][t]       = va > 0.f ? va : 0.f;
            h1[n][t + 256] = vb > 0.f ? vb : 0.f;
        }
    }
    __syncthreads();

    const int o  = t & 127;
    const int nb = (t >> 7) * 8;
    float acc[8] = {};
    for (int c = 0; c < 512; c += 4) {
        const float w0 = W2[(c + 0) * 128 + o];
        const float w1 = W2[(c + 1) * 128 + o];
        const float w2 = W2[(c + 2) * 128 + o];
        const float w3 = W2[(c + 3) * 128 + o];
#pragma unroll
        for (int n = 0; n < 8; ++n) {
            const float4 hv = *reinterpret_cast<const float4*>(&h1[nb + n][c]);
            acc[n] = fmaf(hv.x, w0, acc[n]);
            acc[n] = fmaf(hv.y, w1, acc[n]);
            acc[n] = fmaf(hv.z, w2, acc[n]);
            acc[n] = fmaf(hv.w, w3, acc[n]);
        }
    }

    const float as_ = a2s[o];
    const float ad_ = a2d[o];
    const int head = o >> 5;
    const int lane = t & 63;
#pragma unroll
    for (int n = 0; n < 8; ++n) {
        const int i = i0 + nb + n;
        h2[i * 128 + o] = acc[n];
        float ps = acc[n] * as_;
        float pd = acc[n] * ad_;
#pragma unroll
        for (int sh = 16; sh; sh >>= 1) {
            ps += __shfl_xor(ps, sh);
            pd += __shfl_xor(pd, sh);
        }
        if ((lane & 31) == 0) {
            as2[i * 4 + head] = ps;
            ad2[i * 4 + head] = pd;
        }
    }
}

// K3n: layer-2 attention, gather form. One wave per node, lanes own 2 columns.
// Fuses /z + b2 + relu into the out2 write. No atomics.
__global__ __launch_bounds__(256) void k3_gather(const int* __restrict__ off,
                                                 const int* __restrict__ ssrc,
                                                 const float* __restrict__ h2,
                                                 const float* __restrict__ as2,
                                                 const float* __restrict__ ad2,
                                                 const float* __restrict__ b2,
                                                 float* __restrict__ out2) {
    const int i = blockIdx.x * 4 + (threadIdx.x >> 6);   // node (grid exact)
    const int lane = threadIdx.x & 63;
    const int h0 = lane >> 5;            // head 0/1 for low cols, +2 for high
    const float ad0 = ad2[i * 4 + h0];
    const float ad1 = ad2[i * 4 + 2 + h0];
    float acc0 = 0.f, acc1 = 0.f, z0 = 0.f, z1 = 0.f;
    const int a = off[i], b = off[i + 1];
    for (int j = a; j < b; ++j) {
        const int s = ssrc[j];
        const float w0 = __expf(lrelu(as2[s * 4 + h0] + ad0));
        const float w1 = __expf(lrelu(as2[s * 4 + 2 + h0] + ad1));
        acc0 = fmaf(w0, h2[s * 128 + lane], acc0);
        acc1 = fmaf(w1, h2[s * 128 + 64 + lane], acc1);
        z0 += w0;
        z1 += w1;
    }
    float v0 = acc0 / z0 + b2[lane];
    float v1 = acc1 / z1 + b2[64 + lane];
    out2[i * 128 + lane]      = v0 > 0.f ? v0 : 0.f;
    out2[i * 128 + 64 + lane] = v1 > 0.f ? v1 : 0.f;
}

// K4: mean-pool out2 into gsum/gcnt (batch is sorted; boundary atomics only)
__global__ __launch_bounds__(128) void k4_pool(const float* __restrict__ out2,
                                               const int* __restrict__ batch,
                                               float* __restrict__ gsum,
                                               float* __restrict__ gcnt) {
    const int i0 = blockIdx.x * 64;
    if (i0 >= NN) return;
    const int o = threadIdx.x;
    const int iend = min(i0 + 64, NN);
    float acc = 0.f, cnt = 0.f;
    int gcur = batch[i0];
    for (int i = i0; i < iend; ++i) {
        int g = batch[i];
        if (g != gcur) {
            atomicAdd(&gsum[gcur * 128 + o], acc);
            if (o == 0) atomicAdd(&gcnt[gcur], cnt);
            acc = 0.f; cnt = 0.f; gcur = g;
        }
        acc += out2[i * 128 + o];
        cnt += 1.f;
    }
    atomicAdd(&gsum[gcur * 128 + o], acc);
    if (o == 0) atomicAdd(&gcnt[gcur], cnt);
}

// K5: fc -> batchnorm -> relu -> heads. One block, 256 threads.
__global__ __launch_bounds__(256) void k5_head(const float* __restrict__ gsum,
                                               const float* __restrict__ gcnt,
                                               const float* __restrict__ fcW,
                                               const float* __restrict__ fcb,
                                               const float* __restrict__ gamma,
                                               const float* __restrict__ beta,
                                               const float* __restrict__ heatW,
                                               const float* __restrict__ heatb,
                                               const float* __restrict__ dehydW,
                                               const float* __restrict__ dehydb,
                                               float* __restrict__ out) {
    __shared__ float pl[GG][129];
    __shared__ float fw[128 * 16];
    __shared__ float cwS[GG];
    __shared__ float Y[GG][17];
    __shared__ float P[4][16], Q[4][16];
    __shared__ float muA[16], ivA[16];
    const int t = threadIdx.x;

    if (t < GG) cwS[t] = 1.f / fmaxf(gcnt[t], 1.f);
    for (int idx = t; idx < 128 * 16; idx += 256) fw[idx] = fcW[idx];
    __syncthreads();
    for (int idx = t; idx < GG * 128; idx += 256)
        pl[idx >> 7][idx & 127] = gsum[idx] * cwS[idx >> 7];
    __syncthreads();

    {
        const int g = t >> 2, jq = t & 3;
        float y0 = fcb[jq], y1 = fcb[jq + 4], y2 = fcb[jq + 8], y3 = fcb[jq + 12];
        for (int c = 0; c < 128; ++c) {
            const float p = pl[g][c];
            const float* fr = &fw[c * 16];
            y0 = fmaf(p, fr[jq],      y0);
            y1 = fmaf(p, fr[jq + 4],  y1);
            y2 = fmaf(p, fr[jq + 8],  y2);
            y3 = fmaf(p, fr[jq + 12], y3);
        }
        Y[g][jq] = y0; Y[g][jq + 4] = y1; Y[g][jq + 8] = y2; Y[g][jq + 12] = y3;
    }
    __syncthreads();

    if (t < 64) {
        const int j = t & 15, grp = t >> 4;
        float s = 0.f, q = 0.f;
        for (int k = 0; k < 16; ++k) {
            float v = Y[grp * 16 + k][j];
            s += v; q += v * v;
        }
        P[grp][j] = s; Q[grp][j] = q;
    }
    __syncthreads();
    if (t < 16) {
        float s = P[0][t] + P[1][t] + P[2][t] + P[3][t];
        float q = Q[0][t] + Q[1][t] + Q[2][t] + Q[3][t];
        float mu = s * (1.f / GG);
        float var = q * (1.f / GG) - mu * mu;
        muA[t] = mu;
        ivA[t] = rsqrtf(var + BN_EPS);
    }
    __syncthreads();

    if (t < GG) {
        const int g = t;
        float r[16];
#pragma unroll
        for (int j = 0; j < 16; ++j) {
            float v = (Y[g][j] - muA[j]) * ivA[j] * gamma[j] + beta[j];
            r[j] = v > 0.f ? v : 0.f;
        }
#pragma unroll
        for (int k = 0; k < 3; ++k) {
            float acc = heatb[k];
#pragma unroll
            for (int j = 0; j < 16; ++j) acc = fmaf(r[j], heatW[j * 3 + k], acc);
            out[g * 3 + k] = acc;
        }
#pragma unroll
        for (int k = 0; k < 2; ++k) {
            float acc = dehydb[k];
#pragma unroll
            for (int j = 0; j < 16; ++j) acc = fmaf(r[j], dehydW[j * 2 + k], acc);
            out[GG * 3 + g * 2 + k] = acc;
        }
    }
}

extern "C" void kernel_launch(void* const* d_in, const int* in_sizes, int n_in,
                              void* d_out, int out_size, void* d_ws, size_t ws_size,
                              hipStream_t stream) {
    const float* x      = (const float*)d_in[0];
    const int*   ei     = (const int*)  d_in[1];
    const int*   batch  = (const int*)  d_in[2];
    const float* W1     = (const float*)d_in[3];
    const float* a1s    = (const float*)d_in[4];
    const float* a1d    = (const float*)d_in[5];
    const float* b1     = (const float*)d_in[6];
    const float* W2     = (const float*)d_in[7];
    const float* a2s    = (const float*)d_in[8];
    const float* a2d    = (const float*)d_in[9];
    const float* b2     = (const float*)d_in[10];
    const float* fcW    = (const float*)d_in[11];
    const float* fcb    = (const float*)d_in[12];
    const float* gamma  = (const float*)d_in[13];
    const float* beta   = (const float*)d_in[14];
    const float* heatW  = (const float*)d_in[15];
    const float* heatb  = (const float*)d_in[16];
    const float* dehydW = (const float*)d_in[17];
    const float* dehydb = (const float*)d_in[18];

    float* ws   = (float*)d_ws;
    float* gsum = ws + OFF_GSUM;
    float* gcnt = ws + OFF_GCNT;
    int*   deg  = (int*)(ws + OFF_DEG);
    float* c1   = ws + OFF_C1;
    float* sv   = ws + OFF_SV;
    float* h2   = ws + OFF_H2;
    float* as2  = ws + OFF_AS2;
    float* ad2  = ws + OFF_AD2;
    float* out2 = ws + OFF_OUT2;
    int*   off  = (int*)(ws + OFF_OFFS);
    int*   cur  = (int*)(ws + OFF_CUR);
    int*   ssrc = (int*)(ws + OFF_SSRC);

    // zero gsum/gcnt/deg in one shot
    hipMemsetAsync(ws, 0, (size_t)ZTOTAL * sizeof(float), stream);

    k0_prep<<<1, 128, 0, stream>>>(W1, a1s, a1d, c1);
    s0_hist<<<(ETOT + 255) / 256, 256, 0, stream>>>(ei, deg);
    s1_scan<<<1, 1024, 0, stream>>>(deg, off, cur);
    s2_scatter<<<(ETOT + 255) / 256, 256, 0, stream>>>(ei, cur, ssrc);
    k1_gather<<<(NN + 255) / 256, 256, 0, stream>>>(x, off, ssrc, c1, sv);
    k2_h2<<<NN / K2_NODES, 256, 0, stream>>>(W1, b1, W2, a2s, a2d, sv, h2, as2, ad2);
    k3_gather<<<NN / 4, 256, 0, stream>>>(off, ssrc, h2, as2, ad2, b2, out2);
    k4_pool<<<(NN + 63) / 64, 128, 0, stream>>>(out2, batch, gsum, gcnt);
    k5_head<<<1, 256, 0, stream>>>(gsum, gcnt, fcW, fcb, gamma, beta,
                                   heatW, heatb, dehydW, dehydb,
                                   (float*)d_out);
}

// Round 9
// 260.434 us; speedup vs baseline: 2.8644x; 1.0172x over previous
//
#include <hip/hip_runtime.h>
#include <hip/hip_bf16.h>

// ---------------- problem constants ----------------
#define NN   20000
#define EE_  160000          // raw edges
#define ETOT (EE_ + NN)      // + self loops
#define GG   64
#define H1_  8
#define F1_  64
#define NEG_SLOPE 0.2f
#define BN_EPS 1e-5f

// ---------------- workspace layout (float/int units) ----------------
// zeroed region (single memset): gsum, gcnt, deg
#define OFF_GSUM 0                        // G*128 floats
#define OFF_GCNT (OFF_GSUM + GG*128)      // G floats
#define OFF_DEG  (OFF_GCNT + GG)          // NN ints
#define ZTOTAL   (OFF_DEG + NN)
// non-zeroed region (fully written each call before use)
#define OFF_C1   ((ZTOTAL + 63) & ~63)    // 16 floats
#define OFF_SV   (OFF_C1 + 64)            // NN*8 floats
#define OFF_H2   (OFF_SV + NN*8)          // NN*128 floats
#define OFF_AS2  (OFF_H2 + NN*128)        // NN*4 floats
#define OFF_AD2  (OFF_AS2 + NN*4)         // NN*4 floats
#define OFF_OUT2 (OFF_AD2 + NN*4)         // NN*128 floats
#define OFF_OFFS (OFF_OUT2 + NN*128)      // NN+1 ints
#define OFF_CUR  (OFF_OFFS + NN + 1)      // NN ints
#define OFF_SSRC (OFF_CUR + NN)           // ETOT ints

__device__ __forceinline__ float lrelu(float v) { return v > 0.f ? v : NEG_SLOPE * v; }

// K0: c1 coefficients. 16 pairs (h, src/dst) x 8 lanes each; shfl_xor reduce.
__global__ __launch_bounds__(128) void k0_prep(const float* __restrict__ W1,
                                               const float* __restrict__ a1s,
                                               const float* __restrict__ a1d,
                                               float* __restrict__ c1) {
    const int t = threadIdx.x;
    const int pair = t >> 3;            // 0..15: [0..7]=src, [8..15]=dst
    const int f8 = t & 7;
    const int h = pair & 7;
    const float* a = (pair & 8) ? a1d : a1s;
    float acc = 0.f;
#pragma unroll
    for (int k = 0; k < 8; ++k) {
        int idx = h * F1_ + f8 + 8 * k;
        acc += W1[idx] * a[idx];
    }
#pragma unroll
    for (int sh = 4; sh; sh >>= 1) acc += __shfl_xor(acc, sh);
    if (f8 == 0) c1[pair] = acc;
}

// S0: in-degree histogram over all edges (incl. self loops)
__global__ __launch_bounds__(256) void s0_hist(const int* __restrict__ ei,
                                               int* __restrict__ deg) {
    int e = blockIdx.x * 256 + threadIdx.x;
    if (e >= ETOT) return;
    int d = (e < EE_) ? ei[EE_ + e] : (e - EE_);
    atomicAdd(&deg[d], 1);
}

// S1: exclusive scan of deg[NN] -> off[NN+1]; copy to cur.
__global__ __launch_bounds__(1024) void s1_scan(const int* __restrict__ deg,
                                                int* __restrict__ off,
                                                int* __restrict__ cur) {
    __shared__ int part[1024];
    const int t = threadIdx.x;
    const int base = t * 20;
    int loc[20];
    int sum = 0;
#pragma unroll
    for (int k = 0; k < 20; ++k) {
        int i = base + k;
        int v = (i < NN) ? deg[i] : 0;
        loc[k] = sum;
        sum += v;
    }
    part[t] = sum;
    __syncthreads();
    for (int sh = 1; sh < 1024; sh <<= 1) {
        int v = (t >= sh) ? part[t - sh] : 0;
        __syncthreads();
        part[t] += v;
        __syncthreads();
    }
    const int pbase = (t > 0) ? part[t - 1] : 0;
#pragma unroll
    for (int k = 0; k < 20; ++k) {
        int i = base + k;
        if (i < NN) {
            int o = pbase + loc[k];
            off[i] = o;
            cur[i] = o;
        }
    }
    if (t == 1023) off[NN] = part[1023];
}

// S2: scatter src ids into dst-sorted order
__global__ __launch_bounds__(256) void s2_scatter(const int* __restrict__ ei,
                                                  int* __restrict__ cur,
                                                  int* __restrict__ ssrc) {
    int e = blockIdx.x * 256 + threadIdx.x;
    if (e >= ETOT) return;
    int s, d;
    if (e < EE_) { s = ei[e]; d = ei[EE_ + e]; }
    else         { s = d = e - EE_; }
    int pos = atomicAdd(&cur[d], 1);
    ssrc[pos] = s;
}

// K1n: layer-1 attention, gather form. One thread per node; writes sv = num/z.
__global__ __launch_bounds__(256) void k1_gather(const float* __restrict__ x,
                                                 const int* __restrict__ off,
                                                 const int* __restrict__ ssrc,
                                                 const float* __restrict__ c1,
                                                 float* __restrict__ sv) {
    const int i = blockIdx.x * 256 + threadIdx.x;
    if (i >= NN) return;
    const float xd = x[i];
    float num[H1_] = {}, z[H1_] = {};
    const int a = off[i], b = off[i + 1];
    for (int j = a; j < b; ++j) {
        const int s = ssrc[j];
        const float xs = x[s];
#pragma unroll
        for (int h = 0; h < H1_; ++h) {
            float w = __expf(lrelu(xs * c1[h] + xd * c1[8 + h]));
            num[h] += w * xs;
            z[h] += w;
        }
    }
#pragma unroll
    for (int h = 0; h < H1_; ++h) sv[i * 8 + h] = num[h] / z[h];
}

// K2: 256 threads / 4 waves, 16 nodes per block. Register blocking 4 nodes x 2 cols
// per thread: per wave c-step = 4 broadcast ds_read_b128 feeding 32 FMA (8 FMA/read).
// A wave owns nodes nb..nb+3 across ALL 128 cols (o and o+64).
#define K2_NODES 16
__global__ __launch_bounds__(256) void k2_h2(const float* __restrict__ W1,
                                             const float* __restrict__ b1,
                                             const float* __restrict__ W2,
                                             const float* __restrict__ a2s,
                                             const float* __restrict__ a2d,
                                             const float* __restrict__ svg,
                                             float* __restrict__ h2,
                                             float* __restrict__ as2,
                                             float* __restrict__ ad2) {
    __shared__ float h1[K2_NODES][512];   // 32 KB
    __shared__ float sv[K2_NODES][8];
    const int i0 = blockIdx.x * K2_NODES;
    const int t = threadIdx.x;

    if (t < K2_NODES * 8) {
        int n = t >> 3, h = t & 7;
        sv[n][h] = svg[(i0 + n) * 8 + h];
    }
    __syncthreads();

    // h1 build: thread owns columns t and t+256 for all 16 nodes.
    {
        const float w1a = W1[t],     w1b = W1[t + 256];
        const float b1a = b1[t],     b1b = b1[t + 256];
        const int   ha  = t >> 6,    hb  = (t + 256) >> 6;
#pragma unroll
        for (int n = 0; n < K2_NODES; ++n) {
            float va = fmaf(w1a, sv[n][ha], b1a);
            float vb = fmaf(w1b, sv[n][hb], b1b);
            h1[n][t]       = va > 0.f ? va : 0.f;
            h1[n][t + 256] = vb > 0.f ? vb : 0.f;
        }
    }
    __syncthreads();

    const int o  = t & 63;           // wave-local col; this thread: cols o, o+64
    const int nb = (t >> 6) * 4;     // wave id * 4 nodes
    float acc0[4] = {};              // cols o
    float acc1[4] = {};              // cols o+64
    for (int c = 0; c < 512; c += 4) {
        const float u00 = W2[(c + 0) * 128 + o];
        const float u01 = W2[(c + 1) * 128 + o];
        const float u02 = W2[(c + 2) * 128 + o];
        const float u03 = W2[(c + 3) * 128 + o];
        const float u10 = W2[(c + 0) * 128 + 64 + o];
        const float u11 = W2[(c + 1) * 128 + 64 + o];
        const float u12 = W2[(c + 2) * 128 + 64 + o];
        const float u13 = W2[(c + 3) * 128 + 64 + o];
#pragma unroll
        for (int n = 0; n < 4; ++n) {
            const float4 hv = *reinterpret_cast<const float4*>(&h1[nb + n][c]);
            acc0[n] = fmaf(hv.x, u00, acc0[n]);
            acc0[n] = fmaf(hv.y, u01, acc0[n]);
            acc0[n] = fmaf(hv.z, u02, acc0[n]);
            acc0[n] = fmaf(hv.w, u03, acc0[n]);
            acc1[n] = fmaf(hv.x, u10, acc1[n]);
            acc1[n] = fmaf(hv.y, u11, acc1[n]);
            acc1[n] = fmaf(hv.z, u12, acc1[n]);
            acc1[n] = fmaf(hv.w, u13, acc1[n]);
        }
    }

    // epilogue: h2 store + head dots. Lanes 0..31 hold cols 0..31 (heads 0/2),
    // lanes 32..63 cols 32..63 (heads 1/3); reduce within 32-lane halves.
    const float as0 = a2s[o],      ad0_ = a2d[o];
    const float as1 = a2s[64 + o], ad1_ = a2d[64 + o];
    const int lane = t & 63;
    const int hsel = lane >> 5;      // 0 or 1
#pragma unroll
    for (int n = 0; n < 4; ++n) {
        const int i = i0 + nb + n;
        h2[i * 128 + o]      = acc0[n];
        h2[i * 128 + 64 + o] = acc1[n];
        float p0s = acc0[n] * as0, p0d = acc0[n] * ad0_;
        float p1s = acc1[n] * as1, p1d = acc1[n] * ad1_;
#pragma unroll
        for (int sh = 16; sh; sh >>= 1) {
            p0s += __shfl_xor(p0s, sh);
            p0d += __shfl_xor(p0d, sh);
            p1s += __shfl_xor(p1s, sh);
            p1d += __shfl_xor(p1d, sh);
        }
        if ((lane & 31) == 0) {
            as2[i * 4 + hsel]     = p0s;
            ad2[i * 4 + hsel]     = p0d;
            as2[i * 4 + 2 + hsel] = p1s;
            ad2[i * 4 + 2 + hsel] = p1d;
        }
    }
}

// K3n: layer-2 attention, gather form. One wave per node, lanes own 2 columns.
// Fuses /z + b2 + relu into the out2 write. No atomics.
__global__ __launch_bounds__(256) void k3_gather(const int* __restrict__ off,
                                                 const int* __restrict__ ssrc,
                                                 const float* __restrict__ h2,
                                                 const float* __restrict__ as2,
                                                 const float* __restrict__ ad2,
                                                 const float* __restrict__ b2,
                                                 float* __restrict__ out2) {
    const int i = blockIdx.x * 4 + (threadIdx.x >> 6);   // node (grid exact)
    const int lane = threadIdx.x & 63;
    const int h0 = lane >> 5;            // head 0/1 for low cols, +2 for high
    const float ad0 = ad2[i * 4 + h0];
    const float ad1 = ad2[i * 4 + 2 + h0];
    float acc0 = 0.f, acc1 = 0.f, z0 = 0.f, z1 = 0.f;
    const int a = off[i], b = off[i + 1];
    for (int j = a; j < b; ++j) {
        const int s = ssrc[j];
        const float w0 = __expf(lrelu(as2[s * 4 + h0] + ad0));
        const float w1 = __expf(lrelu(as2[s * 4 + 2 + h0] + ad1));
        acc0 = fmaf(w0, h2[s * 128 + lane], acc0);
        acc1 = fmaf(w1, h2[s * 128 + 64 + lane], acc1);
        z0 += w0;
        z1 += w1;
    }
    float v0 = acc0 / z0 + b2[lane];
    float v1 = acc1 / z1 + b2[64 + lane];
    out2[i * 128 + lane]      = v0 > 0.f ? v0 : 0.f;
    out2[i * 128 + 64 + lane] = v1 > 0.f ? v1 : 0.f;
}

// K4: mean-pool out2 into gsum/gcnt (batch is sorted; boundary atomics only)
__global__ __launch_bounds__(128) void k4_pool(const float* __restrict__ out2,
                                               const int* __restrict__ batch,
                                               float* __restrict__ gsum,
                                               float* __restrict__ gcnt) {
    const int i0 = blockIdx.x * 64;
    if (i0 >= NN) return;
    const int o = threadIdx.x;
    const int iend = min(i0 + 64, NN);
    float acc = 0.f, cnt = 0.f;
    int gcur = batch[i0];
    for (int i = i0; i < iend; ++i) {
        int g = batch[i];
        if (g != gcur) {
            atomicAdd(&gsum[gcur * 128 + o], acc);
            if (o == 0) atomicAdd(&gcnt[gcur], cnt);
            acc = 0.f; cnt = 0.f; gcur = g;
        }
        acc += out2[i * 128 + o];
        cnt += 1.f;
    }
    atomicAdd(&gsum[gcur * 128 + o], acc);
    if (o == 0) atomicAdd(&gcnt[gcur], cnt);
}

// K5: fc -> batchnorm -> relu -> heads. One block, 256 threads.
__global__ __launch_bounds__(256) void k5_head(const float* __restrict__ gsum,
                                               const float* __restrict__ gcnt,
                                               const float* __restrict__ fcW,
                                               const float* __restrict__ fcb,
                                               const float* __restrict__ gamma,
                                               const float* __restrict__ beta,
                                               const float* __restrict__ heatW,
                                               const float* __restrict__ heatb,
                                               const float* __restrict__ dehydW,
                                               const float* __restrict__ dehydb,
                                               float* __restrict__ out) {
    __shared__ float pl[GG][129];
    __shared__ float fw[128 * 16];
    __shared__ float cwS[GG];
    __shared__ float Y[GG][17];
    __shared__ float P[4][16], Q[4][16];
    __shared__ float muA[16], ivA[16];
    const int t = threadIdx.x;

    if (t < GG) cwS[t] = 1.f / fmaxf(gcnt[t], 1.f);
    for (int idx = t; idx < 128 * 16; idx += 256) fw[idx] = fcW[idx];
    __syncthreads();
    for (int idx = t; idx < GG * 128; idx += 256)
        pl[idx >> 7][idx & 127] = gsum[idx] * cwS[idx >> 7];
    __syncthreads();

    {
        const int g = t >> 2, jq = t & 3;
        float y0 = fcb[jq], y1 = fcb[jq + 4], y2 = fcb[jq + 8], y3 = fcb[jq + 12];
        for (int c = 0; c < 128; ++c) {
            const float p = pl[g][c];
            const float* fr = &fw[c * 16];
            y0 = fmaf(p, fr[jq],      y0);
            y1 = fmaf(p, fr[jq + 4],  y1);
            y2 = fmaf(p, fr[jq + 8],  y2);
            y3 = fmaf(p, fr[jq + 12], y3);
        }
        Y[g][jq] = y0; Y[g][jq + 4] = y1; Y[g][jq + 8] = y2; Y[g][jq + 12] = y3;
    }
    __syncthreads();

    if (t < 64) {
        const int j = t & 15, grp = t >> 4;
        float s = 0.f, q = 0.f;
        for (int k = 0; k < 16; ++k) {
            float v = Y[grp * 16 + k][j];
            s += v; q += v * v;
        }
        P[grp][j] = s; Q[grp][j] = q;
    }
    __syncthreads();
    if (t < 16) {
        float s = P[0][t] + P[1][t] + P[2][t] + P[3][t];
        float q = Q[0][t] + Q[1][t] + Q[2][t] + Q[3][t];
        float mu = s * (1.f / GG);
        float var = q * (1.f / GG) - mu * mu;
        muA[t] = mu;
        ivA[t] = rsqrtf(var + BN_EPS);
    }
    __syncthreads();

    if (t < GG) {
        const int g = t;
        float r[16];
#pragma unroll
        for (int j = 0; j < 16; ++j) {
            float v = (Y[g][j] - muA[j]) * ivA[j] * gamma[j] + beta[j];
            r[j] = v > 0.f ? v : 0.f;
        }
#pragma unroll
        for (int k = 0; k < 3; ++k) {
            float acc = heatb[k];
#pragma unroll
            for (int j = 0; j < 16; ++j) acc = fmaf(r[j], heatW[j * 3 + k], acc);
            out[g * 3 + k] = acc;
        }
#pragma unroll
        for (int k = 0; k < 2; ++k) {
            float acc = dehydb[k];
#pragma unroll
            for (int j = 0; j < 16; ++j) acc = fmaf(r[j], dehydW[j * 2 + k], acc);
            out[GG * 3 + g * 2 + k] = acc;
        }
    }
}

extern "C" void kernel_launch(void* const* d_in, const int* in_sizes, int n_in,
                              void* d_out, int out_size, void* d_ws, size_t ws_size,
                              hipStream_t stream) {
    const float* x      = (const float*)d_in[0];
    const int*   ei     = (const int*)  d_in[1];
    const int*   batch  = (const int*)  d_in[2];
    const float* W1     = (const float*)d_in[3];
    const float* a1s    = (const float*)d_in[4];
    const float* a1d    = (const float*)d_in[5];
    const float* b1     = (const float*)d_in[6];
    const float* W2     = (const float*)d_in[7];
    const float* a2s    = (const float*)d_in[8];
    const float* a2d    = (const float*)d_in[9];
    const float* b2     = (const float*)d_in[10];
    const float* fcW    = (const float*)d_in[11];
    const float* fcb    = (const float*)d_in[12];
    const float* gamma  = (const float*)d_in[13];
    const float* beta   = (const float*)d_in[14];
    const float* heatW  = (const float*)d_in[15];
    const float* heatb  = (const float*)d_in[16];
    const float* dehydW = (const float*)d_in[17];
    const float* dehydb = (const float*)d_in[18];

    float* ws   = (float*)d_ws;
    float* gsum = ws + OFF_GSUM;
    float* gcnt = ws + OFF_GCNT;
    int*   deg  = (int*)(ws + OFF_DEG);
    float* c1   = ws + OFF_C1;
    float* sv   = ws + OFF_SV;
    float* h2   = ws + OFF_H2;
    float* as2  = ws + OFF_AS2;
    float* ad2  = ws + OFF_AD2;
    float* out2 = ws + OFF_OUT2;
    int*   off  = (int*)(ws + OFF_OFFS);
    int*   cur  = (int*)(ws + OFF_CUR);
    int*   ssrc = (int*)(ws + OFF_SSRC);

    // zero gsum/gcnt/deg in one shot
    hipMemsetAsync(ws, 0, (size_t)ZTOTAL * sizeof(float), stream);

    k0_prep<<<1, 128, 0, stream>>>(W1, a1s, a1d, c1);
    s0_hist<<<(ETOT + 255) / 256, 256, 0, stream>>>(ei, deg);
    s1_scan<<<1, 1024, 0, stream>>>(deg, off, cur);
    s2_scatter<<<(ETOT + 255) / 256, 256, 0, stream>>>(ei, cur, ssrc);
    k1_gather<<<(NN + 255) / 256, 256, 0, stream>>>(x, off, ssrc, c1, sv);
    k2_h2<<<NN / K2_NODES, 256, 0, stream>>>(W1, b1, W2, a2s, a2d, sv, h2, as2, ad2);
    k3_gather<<<NN / 4, 256, 0, stream>>>(off, ssrc, h2, as2, ad2, b2, out2);
    k4_pool<<<(NN + 63) / 64, 128, 0, stream>>>(out2, batch, gsum, gcnt);
    k5_head<<<1, 256, 0, stream>>>(gsum, gcnt, fcW, fcb, gamma, beta,
                                   heatW, heatb, dehydW, dehydb,
                                   (float*)d_out);
}